// Round 6
// baseline (219.545 us; speedup 1.0000x reference)
//
#include <hip/hip_runtime.h>

#define NSP 32
#define BB  16
#define CC  64
#define HW  (512 * 512)

#define BLOCK  256
#define CHUNK  8192
#define NCHUNK (HW / CHUNK)        // 32
#define KIT    (CHUNK / 4 / BLOCK) // 8 float4-iters per thread per pass
#define STR    (NSP + 1)           // 33: odd float2-stride -> conflict-free banks

// Barrier that drains LDS (lgkmcnt) but NOT vmcnt: all cross-thread deps are
// LDS-only, so prefetched global loads stay in flight across fold phases.
#define BAR() asm volatile("s_waitcnt lgkmcnt(0)\n\ts_barrier" ::: "memory")

// ---------------------------------------------------------------------------
// Segmented sums + counts. Per-thread privatized float2 LDS bins, plain RMW
// (ds atomics measured 7x slower; duplicate-merge measured neutral).
// Depth-2 register prefetch: loads for pass p+2 issue during pass p, so each
// pass's data has a full pass (~15K cyc) of in-flight time before first use.
// ---------------------------------------------------------------------------
__global__ __launch_bounds__(BLOCK) void sp_accum(const float* __restrict__ feats,
                                                  const int*   __restrict__ spidx,
                                                  float*       __restrict__ sums  /*[B][C][NSP]*/,
                                                  float*       __restrict__ counts/*[B][NSP]*/)
{
    __shared__ float2 s_priv[BLOCK][STR];   // 67.6 KB private bins
    __shared__ float2 s_pe[8][NSP];         // partials, even passes
    __shared__ float2 s_po[8][NSP];         // partials, odd passes

    const int tid  = threadIdx.x;
    const int b    = blockIdx.y;
    const int pix0 = blockIdx.x * CHUNK;
    const int bin  = tid & 31;
    const int grp  = tid >> 5;

    float2* row = s_priv[tid];

    // --- own pixel indices -> registers ---
    uchar4 uu[KIT];
    {
        const int4* ip = (const int4*)(spidx + (size_t)b * HW + pix0);
#pragma unroll
        for (int k = 0; k < KIT; ++k) {
            int4 v = ip[k * BLOCK + tid];
            uu[k] = make_uchar4((unsigned char)(v.x & 31), (unsigned char)(v.y & 31),
                                (unsigned char)(v.z & 31), (unsigned char)(v.w & 31));
        }
    }
#pragma unroll
    for (int s = 0; s < STR; ++s) row[s] = make_float2(0.f, 0.f);

    // --- depth-2 prefetch prologue: pass0 -> preA, pass1 -> preB ---
    const float* fb = feats + (size_t)b * CC * HW + pix0;
    float4 preA[KIT][2], preB[KIT][2];
#pragma unroll
    for (int k = 0; k < KIT; ++k) {
        preA[k][0] = ((const float4*)(fb))[k * BLOCK + tid];
        preA[k][1] = ((const float4*)(fb + (size_t)HW))[k * BLOCK + tid];
    }
#pragma unroll
    for (int k = 0; k < KIT; ++k) {
        preB[k][0] = ((const float4*)(fb + (size_t)2 * HW))[k * BLOCK + tid];
        preB[k][1] = ((const float4*)(fb + (size_t)3 * HW))[k * BLOCK + tid];
    }

    // --- fused pixel counts (plain RMW on .x plane; runs under prefetch) ---
#pragma unroll
    for (int k = 0; k < KIT; ++k) {
        row[uu[k].x].x += 1.f;
        row[uu[k].y].x += 1.f;
        row[uu[k].z].x += 1.f;
        row[uu[k].w].x += 1.f;
    }
    BAR();
    {
        float a = 0.f;
#pragma unroll
        for (int m = 0; m < BLOCK / 8; ++m) a += s_priv[grp + m * 8][bin].x;
        s_pe[grp][bin].x = a;
    }
    BAR();
#pragma unroll
    for (int s = 0; s < STR; ++s) row[s] = make_float2(0.f, 0.f);
    if (tid < NSP) {
        float r = 0.f;
#pragma unroll
        for (int g = 0; g < 8; ++g) r += s_pe[g][tid].x;
        atomicAdd(&counts[b * NSP + tid], r);   // fire-and-forget
    }
    // no barrier needed: pass 0's BAR orders the s_pe rewrite after flush reads;
    // rezero vs pass-0 accum is same-thread.

    // --- main channel-pair passes, 2 barriers each, depth-2 pipeline ---
    auto pass = [&](float4 (&pre)[KIT][2], int ch0, float2 (*part)[NSP]) {
        // accumulate this pass from prefetched registers (simple serial RMW)
#pragma unroll
        for (int k = 0; k < KIT; ++k) {
            const uchar4 u = uu[k];
            const float4 a = pre[k][0], c = pre[k][1];
            float2 t;
            t = row[u.x]; t.x += a.x; t.y += c.x; row[u.x] = t;
            t = row[u.y]; t.x += a.y; t.y += c.y; row[u.y] = t;
            t = row[u.z]; t.x += a.z; t.y += c.z; row[u.z] = t;
            t = row[u.w]; t.x += a.w; t.y += c.w; row[u.w] = t;
        }
        // refill THIS buffer for pass p+2 — consumed a full pass later
        if (ch0 + 4 < CC) {
            const float* g0 = fb + (size_t)(ch0 + 4) * HW;
#pragma unroll
            for (int k = 0; k < KIT; ++k) {
                pre[k][0] = ((const float4*)g0)[k * BLOCK + tid];
                pre[k][1] = ((const float4*)(g0 + (size_t)HW))[k * BLOCK + tid];
            }
        }
        BAR();
        // fold 256 private copies: 8 threads per bin, 32 copies each
        {
            float2 acc = make_float2(0.f, 0.f);
#pragma unroll
            for (int m = 0; m < BLOCK / 8; ++m) {
                float2 v = s_priv[grp + m * 8][bin];
                acc.x += v.x; acc.y += v.y;
            }
            part[grp][bin] = acc;
        }
        BAR();
        // rezero own row (ordered vs next same-parity fold by the next BAR)
#pragma unroll
        for (int s = 0; s < STR; ++s) row[s] = make_float2(0.f, 0.f);
        if (tid < NSP) {
            float2 r = part[0][tid];
#pragma unroll
            for (int g = 1; g < 8; ++g) { r.x += part[g][tid].x; r.y += part[g][tid].y; }
            atomicAdd(&sums[((size_t)b * CC + ch0)     * NSP + tid], r.x);  // fire-and-forget
            atomicAdd(&sums[((size_t)b * CC + ch0 + 1) * NSP + tid], r.y);
        }
        // no trailing barrier: partials are parity-double-buffered
    };

    for (int p = 0; p < CC / 2; p += 2) {
        pass(preA, 2 * p,     s_pe);
        pass(preB, 2 * p + 2, s_po);
    }
}

// ---------------------------------------------------------------------------
// Mean + pairwise similarity. One block per batch.
// out layout: sp [B][NSP][C] at 0, sim [B][NSP][NSP] at B*NSP*C
// ---------------------------------------------------------------------------
__global__ __launch_bounds__(BLOCK) void sp_finalize(const float* __restrict__ sums,
                                                     const float* __restrict__ counts,
                                                     float*       __restrict__ out)
{
    __shared__ float s_sp[NSP][CC + 1];
    const int b   = blockIdx.x;
    const int tid = threadIdx.x;

    for (int i = tid; i < NSP * CC; i += BLOCK) {
        int sp = i >> 6, c = i & 63;
        float cnt = counts[b * NSP + sp];
        float s   = sums[((size_t)b * CC + c) * NSP + sp];
        float v   = (cnt > 0.0f) ? (s / cnt) : 0.0f;
        s_sp[sp][c] = v;
        out[(size_t)b * NSP * CC + (size_t)sp * CC + c] = v;
    }
    __syncthreads();

    for (int p = tid; p < NSP * NSP; p += BLOCK) {
        int i = p >> 5, j = p & 31;
        float acc = 0.0f;
#pragma unroll
        for (int c = 0; c < CC; ++c) {
            float d = s_sp[i][c] - s_sp[j][c];
            acc = fmaf(d, d, acc);
        }
        out[(size_t)BB * NSP * CC + (size_t)b * NSP * NSP + p] = 1.0f - 0.5f * acc;
    }
}

// ---------------------------------------------------------------------------
extern "C" void kernel_launch(void* const* d_in, const int* in_sizes, int n_in,
                              void* d_out, int out_size, void* d_ws, size_t ws_size,
                              hipStream_t stream)
{
    const float* feats = (const float*)d_in[0];
    const int*   spidx = (const int*)d_in[1];
    float*       out   = (float*)d_out;

    float* sums   = (float*)d_ws;                     // B*C*NSP = 32768 floats
    float* counts = sums + (size_t)BB * CC * NSP;     // B*NSP   = 512 floats

    hipMemsetAsync(d_ws, 0, ((size_t)BB * CC * NSP + (size_t)BB * NSP) * sizeof(float), stream);

    dim3 g1(NCHUNK, BB);
    sp_accum<<<g1, BLOCK, 0, stream>>>(feats, spidx, sums, counts);

    sp_finalize<<<BB, BLOCK, 0, stream>>>(sums, counts, out);
}